// Round 14
// baseline (553.652 us; speedup 1.0000x reference)
//
#include <hip/hip_runtime.h>

typedef __bf16 bf16x8 __attribute__((ext_vector_type(8)));
typedef float f32x4 __attribute__((ext_vector_type(4)));
typedef unsigned short u16x4 __attribute__((ext_vector_type(4)));

#define NBATCH 8
#define LPTS   16384
#define CDIM   256
#define KANC   64
#define DIN    512
#define H1DIM  128
#define H2DIM  256
#define TM     64

__device__ __forceinline__ unsigned short f2b(float f){
  __bf16 h = (__bf16)f;                 // native v_cvt, RNE
  return __builtin_bit_cast(unsigned short, h);
}

// Barrier WITHOUT vmcnt drain: flush this wave's LDS ops, rendezvous, fence
// the compiler. Outstanding global loads stay in flight.
#define LBAR() do{ \
  asm volatile("s_waitcnt lgkmcnt(0)" ::: "memory"); \
  __builtin_amdgcn_s_barrier(); \
  asm volatile("" ::: "memory"); \
} while(0)

// wt[0..65536) = W1T[128][512]; wt[65536..98304) = W2T[256][128];
// wt[98304..163840) = W3T[256][256]   (all bf16)
__global__ __launch_bounds__(256) void prep_weights(
    const float* __restrict__ W1, const float* __restrict__ W2,
    const float* __restrict__ W3, unsigned short* __restrict__ wt){
  int id = blockIdx.x * 256 + threadIdx.x;
  if (id < 65536){
    int r = id >> 9, c = id & 511;
    wt[id] = f2b(W1[c * 128 + r]);
  } else if (id < 98304){
    int t = id - 65536; int r = t >> 7, c = t & 127;
    wt[id] = f2b(W2[c * 256 + r]);
  } else if (id < 163840){
    int t = id - 98304; int r = t >> 8, c = t & 255;
    wt[id] = f2b(W3[c * 256 + r]);
  }
}

// Rank-11 collapse of the S-half of GEMM1. coef[comb][12][128] f32.
__global__ __launch_bounds__(128) void prep_coef(
    const float* __restrict__ pts0, const float* __restrict__ pts1,
    const int* __restrict__ anc_i, const int* __restrict__ anc_j,
    const float* __restrict__ W1, float* __restrict__ coef){
  const int comb = blockIdx.x;          // 0..15
  const int strm = comb >> 3, n = comb & 7;
  const int col  = threadIdx.x;         // 0..127
  __shared__ float4 anc[64];
  const float* pts  = strm ? pts1 : pts0;
  const int*   anci = strm ? anc_j : anc_i;
  if (col < 64){
    int ai = anci[n * KANC + col];
    const float* ap = pts + ((size_t)n * LPTS + ai) * 3;
    anc[col] = make_float4(ap[0], ap[1], ap[2], 0.f);
  }
  __syncthreads();
  float SX=0,CX=0,SY=0,CY=0,SZ=0,CZ=0,SD=0,ADx=0,ADy=0,ADz=0,CD2=0;
  float SAx=0,SAy=0,SAz=0,SA2=0;
  for (int k = 0; k < KANC; ++k){
    float4 a = anc[k];
    float ak2 = a.x*a.x + a.y*a.y + a.z*a.z;
    float wx = W1[(256 + k) * 128 + col];
    float wy = W1[(320 + k) * 128 + col];
    float wz = W1[(384 + k) * 128 + col];
    float wd = W1[(448 + k) * 128 + col];
    SX += wx; CX += a.x * wx;
    SY += wy; CY += a.y * wy;
    SZ += wz; CZ += a.z * wz;
    SD += wd; ADx += a.x * wd; ADy += a.y * wd; ADz += a.z * wd;
    CD2 += ak2 * wd;
    SAx += a.x; SAy += a.y; SAz += a.z; SA2 += ak2;
  }
  float* cf = coef + (size_t)comb * 12 * 128;
  cf[ 0*128+col]=SX;  cf[ 1*128+col]=CX;  cf[ 2*128+col]=SY;  cf[ 3*128+col]=CY;
  cf[ 4*128+col]=SZ;  cf[ 5*128+col]=CZ;  cf[ 6*128+col]=SD;  cf[ 7*128+col]=ADx;
  cf[ 8*128+col]=ADy; cf[ 9*128+col]=ADz; cf[10*128+col]=CD2;
  if (col == 0) cf[11*128+0] = SAx;
  if (col == 1) cf[11*128+1] = SAy;
  if (col == 2) cf[11*128+2] = SAz;
  if (col == 3) cf[11*128+3] = SA2;
}

// 2 tiles (128 rows) per block; 2048 blocks. 512 threads, LDS 51 KiB.
// R10 phase bodies verbatim; tile-1 feat prefetched in regs across tile-0
// GEMMs; tile-1 Phase-B reductions computed before bar1 (register-only).
__global__ __launch_bounds__(512, 4) void fused(
    const float* __restrict__ feat0, const float* __restrict__ feat1,
    const float* __restrict__ pts0, const float* __restrict__ pts1,
    const int* __restrict__ anc_i, const int* __restrict__ anc_j,
    const float* __restrict__ b1, const float* __restrict__ b2,
    const float* __restrict__ b3, const unsigned short* __restrict__ wt,
    const float* __restrict__ coef, float* __restrict__ out)
{
  __shared__ unsigned short xs[TM * 256];     // 32 KiB: feat tile [64][256]
  __shared__ unsigned short h1s[TM * H1DIM];  // 16 KiB
  __shared__ float scal[TM][12];              // 3 KiB: per-point u_j
  unsigned short* h2s = xs;                   // aliases xs (feat dead post-G1)

  const int tid  = threadIdx.x;
  const int wg   = blockIdx.x;
  const int strm = wg >> 10;
  const int n    = (wg >> 7) & 7;
  const int l0   = (wg & 127) * 128;          // 2 consecutive 64-row tiles

  const float* feat = strm ? feat1 : feat0;
  const float* pts  = strm ? pts1 : pts0;
  const int*   anci = strm ? anc_j : anc_i;
  const float* cf   = coef + (size_t)((strm << 3) | n) * 12 * 128;

  const int lane = tid & 63;
  const int w    = tid >> 6;
  const int lr   = lane & 15;
  const int lg   = lane >> 4;
  const int col1 = w * 16 + lr;               // G1 column
  const int col0 = w * 32;                    // G2/G3 column base
  const unsigned short* wrow1 = wt + col1 * DIN;
  const unsigned short* w2t = wt + 65536;
  const unsigned short* w3t = wt + 98304;

  // ---- top-of-kernel loads (amortized over 2 tiles) ----
  float ax, ay, az;                           // own-lane anchor
  {
    int ai = anci[n * KANC + lane];
    const float* ap = pts + ((size_t)n * LPTS + ai) * 3;
    ax = ap[0]; ay = ap[1]; az = ap[2];
  }
  const float* ppb = pts + ((size_t)n * LPTS + l0 + (tid >> 3)) * 3;
  float px0 = ppb[0],       py0 = ppb[1],       pz0 = ppb[2];
  float px1 = ppb[64*3],    py1 = ppb[64*3+1],  pz1 = ppb[64*3+2];
  float SAx = cf[11*128+0], SAy = cf[11*128+1], SAz = cf[11*128+2], SA2 = cf[11*128+3];
  float cc[11];
  #pragma unroll
  for (int j = 0; j < 11; ++j) cc[j] = cf[j * 128 + col1];
  float bias1 = b1[col1];
  float bias2a = b2[col0 + lr], bias2b = b2[col0 + 16 + lr];
  float bias3a = b3[col0 + lr], bias3b = b3[col0 + 16 + lr];

  // ---- feat tile 0 -> regs ----
  const float4* fb = (const float4*)(feat + ((size_t)n * LPTS + l0) * CDIM);
  float4 fvA[8];
  #pragma unroll
  for (int it = 0; it < 8; ++it) fvA[it] = fb[it * 512 + tid];
  float4 fvB[8];                              // tile 1, loaded in half 0

  // Phase-B reductions for BOTH tiles (register-only, before any barrier)
  float u0a, u0b, u1a, u1b;                   // (u, u2) per tile
  {
    const int sub = tid & 7;
    float s00=0.f,s01=0.f,s02=0.f, s10=0.f,s11=0.f,s12=0.f;
    #pragma unroll
    for (int i = 0; i < 8; ++i){
      int src = sub * 8 + i;
      float akx = __shfl(ax, src, 64);
      float aky = __shfl(ay, src, 64);
      float akz = __shfl(az, src, 64);
      s00 += fabsf(px0 - akx); s01 += fabsf(py0 - aky); s02 += fabsf(pz0 - akz);
      s10 += fabsf(px1 - akx); s11 += fabsf(py1 - aky); s12 += fabsf(pz1 - akz);
    }
    #pragma unroll
    for (int m = 1; m <= 4; m <<= 1){
      s00 += __shfl_xor(s00, m, 64); s01 += __shfl_xor(s01, m, 64);
      s02 += __shfl_xor(s02, m, 64);
      s10 += __shfl_xor(s10, m, 64); s11 += __shfl_xor(s11, m, 64);
      s12 += __shfl_xor(s12, m, 64);
    }
    #pragma unroll
    for (int half = 0; half < 2; ++half){
      float px = half ? px1 : px0, py = half ? py1 : py0, pz = half ? pz1 : pz0;
      float s0 = half ? s10 : s00, s1 = half ? s11 : s01, s2 = half ? s12 : s02;
      float pp2 = px*px + py*py + pz*pz;
      float s3 = 64.f * pp2 - 2.f * (px*SAx + py*SAy + pz*SAz) + SA2;
      float i0 = 1.f/s0, i1 = 1.f/s1, i2 = 1.f/s2, i3 = 1.f/s3;
      float u;
      switch (sub){
        case 0: u = i0 * px;       break;
        case 1: u = -i0;           break;
        case 2: u = i1 * py;       break;
        case 3: u = -i1;           break;
        case 4: u = i2 * pz;       break;
        case 5: u = -i2;           break;
        case 6: u = i3 * pp2;      break;
        default: u = -2.f*i3*px;   break;
      }
      float u2 = (sub == 0) ? -2.f*i3*py : (sub == 1) ? -2.f*i3*pz : i3;
      if (half){ u1a = u; u1b = u2; } else { u0a = u; u0b = u2; }
    }
  }

  #pragma unroll
  for (int half = 0; half < 2; ++half){
    // ---- Phase A: fv regs -> xs (coalesced-origin data, swizzled stores)
    {
      #pragma unroll
      for (int it = 0; it < 8; ++it){
        int flat = it * 512 + tid;
        int r = flat >> 6, c4 = flat & 63;
        float4 v = half ? fvB[it] : fvA[it];
        int e = (r * 256 + c4 * 4) ^ ((r & 7) << 3);
        u16x4 pk = { f2b(v.x), f2b(v.y), f2b(v.z), f2b(v.w) };
        *(u16x4*)&xs[e] = pk;
      }
    }
    // ---- Phase B stores (values precomputed) ----
    {
      const int l = tid >> 3, sub = tid & 7;
      scal[l][sub] = half ? u1a : u0a;
      if (sub < 3) scal[l][8 + sub] = half ? u1b : u0b;
    }
    // ---- issue tile-1 feat prefetch; stays in flight across G1-G3 ----
    if (half == 0){
      const float4* fb1 = fb + 4096;          // next 64 rows
      #pragma unroll
      for (int it = 0; it < 8; ++it) fvB[it] = fb1[it * 512 + tid];
    }
    LBAR();                                   // xs + scal ready

    // ---- GEMM1: feat MFMA (K=256) + rank-11 S-part -> relu -> h1s ----
    {
      f32x4 acc[4] = {};
      #pragma unroll
      for (int kk = 0; kk < 8; ++kk){
        int kb = kk * 32 + lg * 8;
        bf16x8 b = *(const bf16x8*)&wrow1[kb];
        #pragma unroll
        for (int m = 0; m < 4; ++m){
          int row = m * 16 + lr;
          bf16x8 a = *(const bf16x8*)&xs[(row * 256 + kb) ^ ((row & 7) << 3)];
          acc[m] = __builtin_amdgcn_mfma_f32_16x16x32_bf16(a, b, acc[m], 0, 0, 0);
        }
      }
      #pragma unroll
      for (int m = 0; m < 4; ++m){
        #pragma unroll
        for (int r = 0; r < 4; ++r){
          int row = m * 16 + lg * 4 + r;
          f32x4 ua = *(const f32x4*)&scal[row][0];
          f32x4 ub = *(const f32x4*)&scal[row][4];
          f32x4 uc = *(const f32x4*)&scal[row][8];
          float s = acc[m][r] + bias1;
          s += ua[0]*cc[0] + ua[1]*cc[1] + ua[2]*cc[2] + ua[3]*cc[3];
          s += ub[0]*cc[4] + ub[1]*cc[5] + ub[2]*cc[6] + ub[3]*cc[7];
          s += uc[0]*cc[8] + uc[1]*cc[9] + uc[2]*cc[10];
          float v = fmaxf(s, 0.f);
          h1s[(row * H1DIM + col1) ^ ((row & 7) << 3)] = f2b(v);
        }
      }
    }
    LBAR();                                   // h1s ready, xs reads retired

    // ---- GEMM2: h1s[64,128] @ W2 -> relu -> h2s[64,256] ----
    {
      f32x4 acc[4][2] = {};
      #pragma unroll
      for (int kk = 0; kk < 4; ++kk){
        int kb = kk * 32 + lg * 8;
        bf16x8 bf0 = *(const bf16x8*)&w2t[(col0 + lr) * H1DIM + kb];
        bf16x8 bf1 = *(const bf16x8*)&w2t[(col0 + 16 + lr) * H1DIM + kb];
        #pragma unroll
        for (int m = 0; m < 4; ++m){
          int row = m * 16 + lr;
          bf16x8 a = *(const bf16x8*)&h1s[(row * H1DIM + kb) ^ ((row & 7) << 3)];
          acc[m][0] = __builtin_amdgcn_mfma_f32_16x16x32_bf16(a, bf0, acc[m][0], 0, 0, 0);
          acc[m][1] = __builtin_amdgcn_mfma_f32_16x16x32_bf16(a, bf1, acc[m][1], 0, 0, 0);
        }
      }
      #pragma unroll
      for (int nt = 0; nt < 2; ++nt){
        float bias = nt ? bias2b : bias2a;
        int col = col0 + nt * 16 + lr;
        #pragma unroll
        for (int m = 0; m < 4; ++m){
          #pragma unroll
          for (int r = 0; r < 4; ++r){
            int row = m * 16 + lg * 4 + r;
            float v = fmaxf(acc[m][nt][r] + bias, 0.f);
            h2s[(row * H2DIM + col) ^ ((row & 7) << 3)] = f2b(v);
          }
        }
      }
    }
    LBAR();                                   // h2s ready

    // ---- GEMM3: h2s[64,256] @ W3 -> + b3 -> out (f32) ----
    {
      f32x4 acc[4][2] = {};
      #pragma unroll 4
      for (int kk = 0; kk < 8; ++kk){
        int kb = kk * 32 + lg * 8;
        bf16x8 bf0 = *(const bf16x8*)&w3t[(col0 + lr) * H2DIM + kb];
        bf16x8 bf1 = *(const bf16x8*)&w3t[(col0 + 16 + lr) * H2DIM + kb];
        #pragma unroll
        for (int m = 0; m < 4; ++m){
          int row = m * 16 + lr;
          bf16x8 a = *(const bf16x8*)&h2s[(row * H2DIM + kb) ^ ((row & 7) << 3)];
          acc[m][0] = __builtin_amdgcn_mfma_f32_16x16x32_bf16(a, bf0, acc[m][0], 0, 0, 0);
          acc[m][1] = __builtin_amdgcn_mfma_f32_16x16x32_bf16(a, bf1, acc[m][1], 0, 0, 0);
        }
      }
      float* ob = out + (((size_t)strm * NBATCH + n) * LPTS + l0 + half * 64) * CDIM;
      #pragma unroll
      for (int nt = 0; nt < 2; ++nt){
        float bias = nt ? bias3b : bias3a;
        int col = col0 + nt * 16 + lr;
        #pragma unroll
        for (int m = 0; m < 4; ++m){
          #pragma unroll
          for (int r = 0; r < 4; ++r){
            int row = m * 16 + lg * 4 + r;
            ob[(size_t)row * CDIM + col] = acc[m][nt][r] + bias;
          }
        }
      }
    }
    LBAR();                                   // xs(=h2s) reads retired for next half
  }
}

extern "C" void kernel_launch(void* const* d_in, const int* in_sizes, int n_in,
                              void* d_out, int out_size, void* d_ws, size_t ws_size,
                              hipStream_t stream){
  const float* feat0 = (const float*)d_in[0];
  const float* feat1 = (const float*)d_in[1];
  const float* pts0  = (const float*)d_in[2];
  const float* pts1  = (const float*)d_in[3];
  const int*   anci  = (const int*)d_in[4];
  const int*   ancj  = (const int*)d_in[5];
  const float* W1    = (const float*)d_in[6];
  const float* b1    = (const float*)d_in[7];
  const float* W2    = (const float*)d_in[8];
  const float* b2    = (const float*)d_in[9];
  const float* W3    = (const float*)d_in[10];
  const float* b3    = (const float*)d_in[11];
  unsigned short* wt = (unsigned short*)d_ws;
  float* coef = (float*)((char*)d_ws + 163840 * sizeof(unsigned short));
  float* out = (float*)d_out;

  prep_weights<<<640, 256, 0, stream>>>(W1, W2, W3, wt);
  prep_coef<<<16, 128, 0, stream>>>(pts0, pts1, anci, ancj, W1, coef);
  fused<<<2048, 512, 0, stream>>>(feat0, feat1, pts0, pts1, anci, ancj,
                                  b1, b2, b3, wt, coef, out);
}

// Round 15
// 209.218 us; speedup vs baseline: 2.6463x; 2.6463x over previous
//
#include <hip/hip_runtime.h>

typedef __bf16 bf16x8 __attribute__((ext_vector_type(8)));
typedef float f32x4 __attribute__((ext_vector_type(4)));
typedef unsigned short u16x4 __attribute__((ext_vector_type(4)));

#define NBATCH 8
#define LPTS   16384
#define CDIM   256
#define KANC   64
#define DIN    512
#define H1DIM  128
#define H2DIM  256
#define TM     64

__device__ __forceinline__ unsigned short f2b(float f){
  __bf16 h = (__bf16)f;                 // native v_cvt, RNE
  return __builtin_bit_cast(unsigned short, h);
}

// Barrier WITHOUT vmcnt drain: flush this wave's LDS ops, rendezvous, fence
// the compiler. Outstanding global loads stay in flight.
#define LBAR() do{ \
  asm volatile("s_waitcnt lgkmcnt(0)" ::: "memory"); \
  __builtin_amdgcn_s_barrier(); \
  asm volatile("" ::: "memory"); \
} while(0)

// wt[0..65536) = W1T[128][512]; wt[65536..98304) = W2T[256][128];
// wt[98304..163840) = W3T[256][256]   (all bf16)
__global__ __launch_bounds__(256) void prep_weights(
    const float* __restrict__ W1, const float* __restrict__ W2,
    const float* __restrict__ W3, unsigned short* __restrict__ wt){
  int id = blockIdx.x * 256 + threadIdx.x;
  if (id < 65536){
    int r = id >> 9, c = id & 511;
    wt[id] = f2b(W1[c * 128 + r]);
  } else if (id < 98304){
    int t = id - 65536; int r = t >> 7, c = t & 127;
    wt[id] = f2b(W2[c * 256 + r]);
  } else if (id < 163840){
    int t = id - 98304; int r = t >> 8, c = t & 255;
    wt[id] = f2b(W3[c * 256 + r]);
  }
}

// Rank-11 collapse of the S-half of GEMM1. coef[comb][12][128] f32.
__global__ __launch_bounds__(128) void prep_coef(
    const float* __restrict__ pts0, const float* __restrict__ pts1,
    const int* __restrict__ anc_i, const int* __restrict__ anc_j,
    const float* __restrict__ W1, float* __restrict__ coef){
  const int comb = blockIdx.x;          // 0..15
  const int strm = comb >> 3, n = comb & 7;
  const int col  = threadIdx.x;         // 0..127
  __shared__ float4 anc[64];
  const float* pts  = strm ? pts1 : pts0;
  const int*   anci = strm ? anc_j : anc_i;
  if (col < 64){
    int ai = anci[n * KANC + col];
    const float* ap = pts + ((size_t)n * LPTS + ai) * 3;
    anc[col] = make_float4(ap[0], ap[1], ap[2], 0.f);
  }
  __syncthreads();
  float SX=0,CX=0,SY=0,CY=0,SZ=0,CZ=0,SD=0,ADx=0,ADy=0,ADz=0,CD2=0;
  float SAx=0,SAy=0,SAz=0,SA2=0;
  for (int k = 0; k < KANC; ++k){
    float4 a = anc[k];
    float ak2 = a.x*a.x + a.y*a.y + a.z*a.z;
    float wx = W1[(256 + k) * 128 + col];
    float wy = W1[(320 + k) * 128 + col];
    float wz = W1[(384 + k) * 128 + col];
    float wd = W1[(448 + k) * 128 + col];
    SX += wx; CX += a.x * wx;
    SY += wy; CY += a.y * wy;
    SZ += wz; CZ += a.z * wz;
    SD += wd; ADx += a.x * wd; ADy += a.y * wd; ADz += a.z * wd;
    CD2 += ak2 * wd;
    SAx += a.x; SAy += a.y; SAz += a.z; SA2 += ak2;
  }
  float* cf = coef + (size_t)comb * 12 * 128;
  cf[ 0*128+col]=SX;  cf[ 1*128+col]=CX;  cf[ 2*128+col]=SY;  cf[ 3*128+col]=CY;
  cf[ 4*128+col]=SZ;  cf[ 5*128+col]=CZ;  cf[ 6*128+col]=SD;  cf[ 7*128+col]=ADx;
  cf[ 8*128+col]=ADy; cf[ 9*128+col]=ADz; cf[10*128+col]=CD2;
  if (col == 0) cf[11*128+0] = SAx;
  if (col == 1) cf[11*128+1] = SAy;
  if (col == 2) cf[11*128+2] = SAz;
  if (col == 3) cf[11*128+3] = SA2;
}

// TM=64, 512 threads (8 waves, GEMMs 1M x 8N). LDS 51 KiB. 3 LBAR barriers.
// B-operands batch-loaded into static arrays before each MFMA loop so the
// independent L2 loads overlap each other (counted vmcnt waits).
__global__ __launch_bounds__(512, 4) void fused(
    const float* __restrict__ feat0, const float* __restrict__ feat1,
    const float* __restrict__ pts0, const float* __restrict__ pts1,
    const int* __restrict__ anc_i, const int* __restrict__ anc_j,
    const float* __restrict__ b1, const float* __restrict__ b2,
    const float* __restrict__ b3, const unsigned short* __restrict__ wt,
    const float* __restrict__ coef, float* __restrict__ out)
{
  __shared__ unsigned short xs[TM * 256];     // 32 KiB: feat tile [64][256]
  __shared__ unsigned short h1s[TM * H1DIM];  // 16 KiB
  __shared__ float scal[TM][12];              // 3 KiB: per-point u_j
  unsigned short* h2s = xs;                   // aliases xs (feat dead post-G1)

  const int tid  = threadIdx.x;
  const int wg   = blockIdx.x;
  const int strm = wg >> 11;
  const int n    = (wg >> 8) & 7;
  const int l0   = (wg & 255) * TM;

  const float* feat = strm ? feat1 : feat0;
  const float* pts  = strm ? pts1 : pts0;
  const int*   anci = strm ? anc_j : anc_i;
  const float* cf   = coef + (size_t)((strm << 3) | n) * 12 * 128;

  const int lane = tid & 63;
  const int w    = tid >> 6;
  const int lr   = lane & 15;
  const int lg   = lane >> 4;
  const int col1 = w * 16 + lr;               // G1 column
  const int col0 = w * 32;                    // G2/G3 column base
  const unsigned short* wrow1 = wt + col1 * DIN;
  const unsigned short* w2t = wt + 65536;
  const unsigned short* w3t = wt + 98304;

  // ---- top-of-kernel scalar/point loads ----
  float ax, ay, az;                           // own-lane anchor
  {
    int ai = anci[n * KANC + lane];
    const float* ap = pts + ((size_t)n * LPTS + ai) * 3;
    ax = ap[0]; ay = ap[1]; az = ap[2];
  }
  const float* pp = pts + ((size_t)n * LPTS + l0 + (tid >> 3)) * 3;
  float px = pp[0], py = pp[1], pz = pp[2];
  float SAx = cf[11*128+0], SAy = cf[11*128+1], SAz = cf[11*128+2], SA2 = cf[11*128+3];
  float cc[11];
  #pragma unroll
  for (int j = 0; j < 11; ++j) cc[j] = cf[j * 128 + col1];
  float bias1 = b1[col1];

  // ---- Phase A: feat tile -> xs[64][256] bf16 (coalesced, swizzled) ----
  {
    const float4* fb = (const float4*)(feat + ((size_t)n * LPTS + l0) * CDIM);
    #pragma unroll
    for (int it = 0; it < 8; ++it){
      int flat = it * 512 + tid;          // 4096 float4, 16B/lane coalesced
      int r = flat >> 6, c4 = flat & 63;
      float4 v = fb[flat];
      int e = (r * 256 + c4 * 4) ^ ((r & 7) << 3);
      u16x4 pk = { f2b(v.x), f2b(v.y), f2b(v.z), f2b(v.w) };
      *(u16x4*)&xs[e] = pk;
    }
  }

  // ---- Phase B: L1 denominators via shfl + per-point scalars -> scal ----
  {
    const int l   = tid >> 3;             // 0..63
    const int sub = tid & 7;
    float s0 = 0.f, s1 = 0.f, s2 = 0.f;
    #pragma unroll
    for (int i = 0; i < 8; ++i){
      int src = sub * 8 + i;
      float akx = __shfl(ax, src, 64);
      float aky = __shfl(ay, src, 64);
      float akz = __shfl(az, src, 64);
      s0 += fabsf(px - akx); s1 += fabsf(py - aky); s2 += fabsf(pz - akz);
    }
    #pragma unroll
    for (int m = 1; m <= 4; m <<= 1){
      s0 += __shfl_xor(s0, m, 64);
      s1 += __shfl_xor(s1, m, 64);
      s2 += __shfl_xor(s2, m, 64);
    }
    float pp2 = px*px + py*py + pz*pz;
    float s3 = 64.f * pp2 - 2.f * (px*SAx + py*SAy + pz*SAz) + SA2;
    float i0 = 1.f/s0, i1 = 1.f/s1, i2 = 1.f/s2, i3 = 1.f/s3;
    float u;
    switch (sub){
      case 0: u = i0 * px;       break;
      case 1: u = -i0;           break;
      case 2: u = i1 * py;       break;
      case 3: u = -i1;           break;
      case 4: u = i2 * pz;       break;
      case 5: u = -i2;           break;
      case 6: u = i3 * pp2;      break;
      default: u = -2.f*i3*px;   break;
    }
    scal[l][sub] = u;
    if (sub < 3){
      float u2 = (sub == 0) ? -2.f*i3*py : (sub == 1) ? -2.f*i3*pz : i3;
      scal[l][8 + sub] = u2;
    }
  }

  // ---- G1 B-batch: 8 independent L2 loads, issued before bar1 ----
  bf16x8 b1b[8];
  #pragma unroll
  for (int kk = 0; kk < 8; ++kk)
    b1b[kk] = *(const bf16x8*)&wrow1[kk * 32 + lg * 8];

  LBAR();                                 // bar1: xs + scal ready

  // ---- GEMM1: feat MFMA (K=256) + rank-11 S-part -> relu -> h1s ----
  {
    f32x4 acc[4] = {};
    #pragma unroll
    for (int kk = 0; kk < 8; ++kk){
      int kb = kk * 32 + lg * 8;
      #pragma unroll
      for (int m = 0; m < 4; ++m){
        int row = m * 16 + lr;
        bf16x8 a = *(const bf16x8*)&xs[(row * 256 + kb) ^ ((row & 7) << 3)];
        acc[m] = __builtin_amdgcn_mfma_f32_16x16x32_bf16(a, b1b[kk], acc[m], 0, 0, 0);
      }
    }
    #pragma unroll
    for (int m = 0; m < 4; ++m){
      #pragma unroll
      for (int r = 0; r < 4; ++r){
        int row = m * 16 + lg * 4 + r;
        f32x4 ua = *(const f32x4*)&scal[row][0];
        f32x4 ub = *(const f32x4*)&scal[row][4];
        f32x4 uc = *(const f32x4*)&scal[row][8];
        float s = acc[m][r] + bias1;
        s += ua[0]*cc[0] + ua[1]*cc[1] + ua[2]*cc[2] + ua[3]*cc[3];
        s += ub[0]*cc[4] + ub[1]*cc[5] + ub[2]*cc[6] + ub[3]*cc[7];
        s += uc[0]*cc[8] + uc[1]*cc[9] + uc[2]*cc[10];
        float v = fmaxf(s, 0.f);
        h1s[(row * H1DIM + col1) ^ ((row & 7) << 3)] = f2b(v);
      }
    }
  }

  // ---- G2 B-batch: 8 loads (4 kk x 2 cols), issued before bar2 ----
  bf16x8 b2b[8];
  #pragma unroll
  for (int kk = 0; kk < 4; ++kk){
    int kb = kk * 32 + lg * 8;
    b2b[kk * 2    ] = *(const bf16x8*)&w2t[(col0      + lr) * H1DIM + kb];
    b2b[kk * 2 + 1] = *(const bf16x8*)&w2t[(col0 + 16 + lr) * H1DIM + kb];
  }

  LBAR();                                 // bar2: h1s ready, xs reads retired

  // ---- GEMM2: h1s[64,128] @ W2 -> relu -> h2s[64,256] (aliases xs) ----
  {
    f32x4 acc[4][2] = {};
    #pragma unroll
    for (int kk = 0; kk < 4; ++kk){
      int kb = kk * 32 + lg * 8;
      #pragma unroll
      for (int m = 0; m < 4; ++m){
        int row = m * 16 + lr;
        bf16x8 a = *(const bf16x8*)&h1s[(row * H1DIM + kb) ^ ((row & 7) << 3)];
        acc[m][0] = __builtin_amdgcn_mfma_f32_16x16x32_bf16(a, b2b[kk*2  ], acc[m][0], 0, 0, 0);
        acc[m][1] = __builtin_amdgcn_mfma_f32_16x16x32_bf16(a, b2b[kk*2+1], acc[m][1], 0, 0, 0);
      }
    }
    #pragma unroll
    for (int nt = 0; nt < 2; ++nt){
      int col = col0 + nt * 16 + lr;
      float bias = b2[col];
      #pragma unroll
      for (int m = 0; m < 4; ++m){
        #pragma unroll
        for (int r = 0; r < 4; ++r){
          int row = m * 16 + lg * 4 + r;
          float v = fmaxf(acc[m][nt][r] + bias, 0.f);
          h2s[(row * H2DIM + col) ^ ((row & 7) << 3)] = f2b(v);
        }
      }
    }
  }

  // ---- G3 B-batch 1: 8 loads (kk=0..3 x 2 cols), issued before bar3 ----
  bf16x8 b3b[8];
  #pragma unroll
  for (int kk = 0; kk < 4; ++kk){
    int kb = kk * 32 + lg * 8;
    b3b[kk * 2    ] = *(const bf16x8*)&w3t[(col0      + lr) * H2DIM + kb];
    b3b[kk * 2 + 1] = *(const bf16x8*)&w3t[(col0 + 16 + lr) * H2DIM + kb];
  }

  LBAR();                                 // bar3: h2s ready

  // ---- GEMM3: h2s[64,256] @ W3 -> + b3 -> out (f32) ----
  {
    f32x4 acc[4][2] = {};
    #pragma unroll
    for (int kk = 0; kk < 4; ++kk){
      int kb = kk * 32 + lg * 8;
      #pragma unroll
      for (int m = 0; m < 4; ++m){
        int row = m * 16 + lr;
        bf16x8 a = *(const bf16x8*)&h2s[(row * H2DIM + kb) ^ ((row & 7) << 3)];
        acc[m][0] = __builtin_amdgcn_mfma_f32_16x16x32_bf16(a, b3b[kk*2  ], acc[m][0], 0, 0, 0);
        acc[m][1] = __builtin_amdgcn_mfma_f32_16x16x32_bf16(a, b3b[kk*2+1], acc[m][1], 0, 0, 0);
      }
    }
    // second B-batch (kk=4..7); latency hides under batch-1 MFMAs above
    #pragma unroll
    for (int kk = 0; kk < 4; ++kk){
      int kb = (kk + 4) * 32 + lg * 8;
      b3b[kk * 2    ] = *(const bf16x8*)&w3t[(col0      + lr) * H2DIM + kb];
      b3b[kk * 2 + 1] = *(const bf16x8*)&w3t[(col0 + 16 + lr) * H2DIM + kb];
    }
    #pragma unroll
    for (int kk = 0; kk < 4; ++kk){
      int kb = (kk + 4) * 32 + lg * 8;
      #pragma unroll
      for (int m = 0; m < 4; ++m){
        int row = m * 16 + lr;
        bf16x8 a = *(const bf16x8*)&h2s[(row * H2DIM + kb) ^ ((row & 7) << 3)];
        acc[m][0] = __builtin_amdgcn_mfma_f32_16x16x32_bf16(a, b3b[kk*2  ], acc[m][0], 0, 0, 0);
        acc[m][1] = __builtin_amdgcn_mfma_f32_16x16x32_bf16(a, b3b[kk*2+1], acc[m][1], 0, 0, 0);
      }
    }
    float* ob = out + (((size_t)strm * NBATCH + n) * LPTS + l0) * CDIM;
    #pragma unroll
    for (int nt = 0; nt < 2; ++nt){
      int col = col0 + nt * 16 + lr;
      float bias = b3[col];
      #pragma unroll
      for (int m = 0; m < 4; ++m){
        #pragma unroll
        for (int r = 0; r < 4; ++r){
          int row = m * 16 + lg * 4 + r;
          ob[(size_t)row * CDIM + col] = acc[m][nt][r] + bias;
        }
      }
    }
  }
}

extern "C" void kernel_launch(void* const* d_in, const int* in_sizes, int n_in,
                              void* d_out, int out_size, void* d_ws, size_t ws_size,
                              hipStream_t stream){
  const float* feat0 = (const float*)d_in[0];
  const float* feat1 = (const float*)d_in[1];
  const float* pts0  = (const float*)d_in[2];
  const float* pts1  = (const float*)d_in[3];
  const int*   anci  = (const int*)d_in[4];
  const int*   ancj  = (const int*)d_in[5];
  const float* W1    = (const float*)d_in[6];
  const float* b1    = (const float*)d_in[7];
  const float* W2    = (const float*)d_in[8];
  const float* b2    = (const float*)d_in[9];
  const float* W3    = (const float*)d_in[10];
  const float* b3    = (const float*)d_in[11];
  unsigned short* wt = (unsigned short*)d_ws;
  float* coef = (float*)((char*)d_ws + 163840 * sizeof(unsigned short));
  float* out = (float*)d_out;

  prep_weights<<<640, 256, 0, stream>>>(W1, W2, W3, wt);
  prep_coef<<<16, 128, 0, stream>>>(pts0, pts1, anci, ancj, W1, coef);
  fused<<<4096, 512, 0, stream>>>(feat0, feat1, pts0, pts1, anci, ancj,
                                  b1, b2, b3, wt, coef, out);
}